// Round 1
// baseline (834.153 us; speedup 1.0000x reference)
//
#include <hip/hip_runtime.h>
#include <hip/hip_bf16.h>
#include <stdint.h>

// IDFT as one real GEMM:  C(32768 x 2048) = A(32768 x 2048) * B(2048 x 2048)
//   A = [re | im] along K;  B = [[Mr, Mi], [-Mi, Mr]]
//   C cols 0..1023 -> y_real, cols 1024..2047 -> y_imag
// bf16 MFMA (16x16x32), fp32 accumulate. Threshold 3.6e-3 >> expected ~2e-4.

typedef __attribute__((ext_vector_type(4))) float f32x4;
typedef __attribute__((ext_vector_type(8))) short bf16x8;

typedef const __attribute__((address_space(1))) void* gas_ptr;
typedef __attribute__((address_space(3))) void* las_ptr;

static __device__ __forceinline__ short f2bf(float f) {
  __hip_bfloat16 h = __float2bfloat16(f);
  return *reinterpret_cast<short*>(&h);
}

// ---------------------------------------------------------------------------
// Prologue: build B^T (2048 x 2048, bf16, row-major [n][k]) into d_ws.
//   BT[n][k] =  Mr[k][n]        (k<1024, n<1024)
//               Mi[k][n-1024]   (k<1024, n>=1024)
//              -Mi[k-1024][n]   (k>=1024, n<1024)
//               Mr[k-1024][n-1024] (both >= 1024)
// 64x64 LDS-tiled transpose, fully coalesced both sides. ~24 MB traffic.
// ---------------------------------------------------------------------------
__global__ __launch_bounds__(256) void build_bt(const float* __restrict__ fr,
                                                const float* __restrict__ fi,
                                                __hip_bfloat16* __restrict__ bt) {
  __shared__ float tile[64][65];
  const int bid = blockIdx.x;            // 32 x 32 tiles of 64x64
  const int ktile = (bid >> 5) << 6;     // 0..2047
  const int ntile = (bid & 31) << 6;
  const bool kq = ktile >= 1024, nq = ntile >= 1024;
  const float* src = (kq == nq) ? fr : fi;
  const float sgn = (kq && !nq) ? -1.f : 1.f;
  const int ks = ktile & 1023, ns = ntile & 1023;
  const int tid = threadIdx.x;

#pragma unroll
  for (int i = 0; i < 16; ++i) {
    int flat = i * 256 + tid;
    int lk = flat >> 6, ln = flat & 63;
    tile[lk][ln] = src[(size_t)(ks + lk) * 1024 + ns + ln];
  }
  __syncthreads();
#pragma unroll
  for (int i = 0; i < 16; ++i) {
    int flat = i * 256 + tid;
    int ln = flat >> 6, lk = flat & 63;
    bt[(size_t)(ntile + ln) * 2048 + ktile + lk] =
        __float2bfloat16(sgn * tile[lk][ln]);
  }
}

// ---------------------------------------------------------------------------
// Main GEMM: 128x128 tile, BK=64, 4 waves (2x2), each wave 64x64 = 4x4 frags.
// LDS XOR-swizzle (T2): byte ^= ((row&7)<<4) within each 128-B row.
//   A: reg-staged (fp32->bf16 convert) with swizzled ds_write_b128.
//   B: global_load_lds width=16, linear LDS dest + inverse-swizzled source.
// ---------------------------------------------------------------------------
__global__ __launch_bounds__(256, 2)
void cgemm(const float* __restrict__ re, const float* __restrict__ im,
           const __hip_bfloat16* __restrict__ bt, float* __restrict__ out) {
  __shared__ short Alds[128 * 64];  // [row 0..127][k 0..63] bf16, swizzled
  __shared__ short Blds[128 * 64];  // [n 0..127][k 0..63]  bf16, swizzled

  const int tid = threadIdx.x;
  const int lane = tid & 63;
  const int wid = tid >> 6;
  const int wr = wid >> 1, wc = wid & 1;  // wave 2x2 grid
  const int fr_ = lane & 15;              // fragment row/col within 16
  const int fq = lane >> 4;               // 0..3

  // XCD-aware swizzle (nwg = 4096, divisible by 8), n-tile fastest.
  const int nwg = gridDim.x;
  const int bid = blockIdx.x;
  const int swz = (bid & 7) * (nwg >> 3) + (bid >> 3);
  const int mt = swz >> 4;   // 0..255
  const int nt = swz & 15;   // 0..15
  const size_t mbase = (size_t)mt * 128;
  const int nbase = nt * 128;  // 0..2047

  f32x4 acc[4][4];
  const f32x4 zero = {0.f, 0.f, 0.f, 0.f};
#pragma unroll
  for (int i = 0; i < 4; ++i)
#pragma unroll
    for (int j = 0; j < 4; ++j) acc[i][j] = zero;

  // A staging geometry: thread -> (row = i*32 + tid/8, k = (tid&7)*8 .. +7)
  const int arow_l = tid >> 3;
  const int akc = (tid & 7) * 8;
  const size_t aoff = (mbase + arow_l) * 1024 + akc;
  const char* btbase = (const char*)bt + (size_t)nbase * 4096;  // row stride 4096 B

  for (int kt = 0; kt < 32; ++kt) {
    const int k0 = kt * 64;
    const float* asrc = (k0 < 1024) ? re : im;
    const int kk = k0 & 1023;

    __syncthreads();  // previous tile's reads complete

    // ---- stage B: 4 x global_load_lds(16B). LDS dest linear in lane order;
    //      swizzle realized by XOR on the GLOBAL source byte offset (m173).
    const char* bsrc = btbase + (size_t)k0 * 2;
#pragma unroll
    for (int i = 0; i < 4; ++i) {
      int chunk = i * 256 + tid;          // 16-B chunk id in the 16-KB tile
      int n = chunk >> 3;                 // LDS row (0..127)
      int kb = (chunk & 7) * 16;          // byte within 128-B row
      int srcoff = n * 4096 + (kb ^ ((n & 7) << 4));
      __builtin_amdgcn_global_load_lds((gas_ptr)(bsrc + srcoff),
                                       (las_ptr)((char*)Blds + chunk * 16),
                                       16, 0, 0);
    }

    // ---- stage A: load fp32, convert, swizzled ds_write_b128
#pragma unroll
    for (int i = 0; i < 4; ++i) {
      int row = i * 32 + arow_l;
      const float* p = asrc + aoff + (size_t)i * 32 * 1024 + kk;
      f32x4 v0 = *(const f32x4*)p;
      f32x4 v1 = *(const f32x4*)(p + 4);
      bf16x8 h;
      h[0] = f2bf(v0[0]); h[1] = f2bf(v0[1]); h[2] = f2bf(v0[2]); h[3] = f2bf(v0[3]);
      h[4] = f2bf(v1[0]); h[5] = f2bf(v1[1]); h[6] = f2bf(v1[2]); h[7] = f2bf(v1[3]);
      int byte = (row * 128 + akc * 2) ^ ((row & 7) << 4);
      *reinterpret_cast<bf16x8*>(reinterpret_cast<char*>(Alds) + byte) = h;
    }

    __syncthreads();  // staged data visible (drains vmcnt+lgkmcnt)

    // ---- compute: 2 k-subtiles x 4x4 MFMAs
#pragma unroll
    for (int ks = 0; ks < 2; ++ks) {
      bf16x8 af[4], bfr[4];
      const int koff = ks * 64 + fq * 16;
#pragma unroll
      for (int mi = 0; mi < 4; ++mi) {
        int row = wr * 64 + mi * 16 + fr_;
        int byte = (row * 128 + koff) ^ ((row & 7) << 4);
        af[mi] = *reinterpret_cast<const bf16x8*>(
            reinterpret_cast<const char*>(Alds) + byte);
      }
#pragma unroll
      for (int ni = 0; ni < 4; ++ni) {
        int row = wc * 64 + ni * 16 + fr_;
        int byte = (row * 128 + koff) ^ ((row & 7) << 4);
        bfr[ni] = *reinterpret_cast<const bf16x8*>(
            reinterpret_cast<const char*>(Blds) + byte);
      }
#pragma unroll
      for (int mi = 0; mi < 4; ++mi)
#pragma unroll
        for (int ni = 0; ni < 4; ++ni)
          acc[mi][ni] = __builtin_amdgcn_mfma_f32_16x16x32_bf16(
              af[mi], bfr[ni], acc[mi][ni], 0, 0, 0);
    }
  }

  // ---- epilogue: C/D layout col=lane&15, row=(lane>>4)*4+reg (m89-verified)
  const size_t half = (size_t)32768 * 1024;
  float* ob = out + ((nbase >= 1024) ? half : 0);
  const int ncol0 = nbase & 1023;
#pragma unroll
  for (int mi = 0; mi < 4; ++mi) {
#pragma unroll
    for (int ni = 0; ni < 4; ++ni) {
      int colg = ncol0 + wc * 64 + ni * 16 + fr_;
      size_t rbase = mbase + wr * 64 + mi * 16 + fq * 4;
#pragma unroll
      for (int j = 0; j < 4; ++j)
        ob[(rbase + j) * 1024 + colg] = acc[mi][ni][j];
    }
  }
}

extern "C" void kernel_launch(void* const* d_in, const int* in_sizes, int n_in,
                              void* d_out, int out_size, void* d_ws, size_t ws_size,
                              hipStream_t stream) {
  const float* re = (const float*)d_in[0];
  const float* im = (const float*)d_in[1];
  const float* fr = (const float*)d_in[2];
  const float* fi = (const float*)d_in[3];
  float* out = (float*)d_out;

  // d_ws: B^T bf16, 2048*2048*2 = 8 MB (re-built every call; ws re-poisoned)
  __hip_bfloat16* bt = (__hip_bfloat16*)d_ws;

  build_bt<<<1024, 256, 0, stream>>>(fr, fi, bt);

  // grid: 256 m-tiles x 16 n-tiles = 4096 blocks
  cgemm<<<4096, 256, 0, stream>>>(re, im, bt, out);
}

// Round 2
// 730.579 us; speedup vs baseline: 1.1418x; 1.1418x over previous
//
#include <hip/hip_runtime.h>
#include <hip/hip_bf16.h>
#include <stdint.h>

// IDFT as one real GEMM:  C(32768 x 2048) = A(32768 x 2048) * B(2048 x 2048)
//   A = [re | im] along K;  B = [[Mr, Mi], [-Mi, Mr]]
//   C cols 0..1023 -> y_real, cols 1024..2047 -> y_imag
// Round 2: A converted to bf16 in a streaming prologue so the GEMM is pure
// m97-structure (both operands via global_load_lds w=16, swizzled source).

typedef __attribute__((ext_vector_type(4))) float f32x4;
typedef __attribute__((ext_vector_type(8))) short bf16x8;

typedef const __attribute__((address_space(1))) void* gas_ptr;
typedef __attribute__((address_space(3))) void* las_ptr;

static __device__ __forceinline__ short f2bf(float f) {
  __hip_bfloat16 h = __float2bfloat16(f);
  return *reinterpret_cast<short*>(&h);
}

// ---------------------------------------------------------------------------
// Prologue 1: build B^T (2048 x 2048, bf16, row-major [n][k]) into ws.
// ---------------------------------------------------------------------------
__global__ __launch_bounds__(256) void build_bt(const float* __restrict__ fr,
                                                const float* __restrict__ fi,
                                                __hip_bfloat16* __restrict__ bt) {
  __shared__ float tile[64][65];
  const int bid = blockIdx.x;            // 32 x 32 tiles of 64x64
  const int ktile = (bid >> 5) << 6;     // 0..2047
  const int ntile = (bid & 31) << 6;
  const bool kq = ktile >= 1024, nq = ntile >= 1024;
  const float* src = (kq == nq) ? fr : fi;
  const float sgn = (kq && !nq) ? -1.f : 1.f;
  const int ks = ktile & 1023, ns = ntile & 1023;
  const int tid = threadIdx.x;

#pragma unroll
  for (int i = 0; i < 16; ++i) {
    int flat = i * 256 + tid;
    int lk = flat >> 6, ln = flat & 63;
    tile[lk][ln] = src[(size_t)(ks + lk) * 1024 + ns + ln];
  }
  __syncthreads();
#pragma unroll
  for (int i = 0; i < 16; ++i) {
    int flat = i * 256 + tid;
    int ln = flat >> 6, lk = flat & 63;
    bt[(size_t)(ntile + ln) * 2048 + ktile + lk] =
        __float2bfloat16(sgn * tile[lk][ln]);
  }
}

// ---------------------------------------------------------------------------
// Prologue 2: A -> bf16, combined [m][k] (k<1024: re, k>=1024: im).
// Streaming, fully vectorized: 16B loads x2, 16B store per chunk of 8.
// ---------------------------------------------------------------------------
__global__ __launch_bounds__(256) void convert_a(const float* __restrict__ re,
                                                 const float* __restrict__ im,
                                                 __hip_bfloat16* __restrict__ abf) {
  const int64_t total = (int64_t)32768 * 256;  // 8-elem chunks, 256 per row
  for (int64_t c = (int64_t)blockIdx.x * 256 + threadIdx.x; c < total;
       c += (int64_t)gridDim.x * 256) {
    int64_t m = c >> 8;
    int kc = (int)(c & 255) * 8;
    const float* src = (kc < 1024) ? re : im;
    const float* p = src + m * 1024 + (kc & 1023);
    f32x4 v0 = *(const f32x4*)p;
    f32x4 v1 = *(const f32x4*)(p + 4);
    bf16x8 h;
    h[0] = f2bf(v0[0]); h[1] = f2bf(v0[1]); h[2] = f2bf(v0[2]); h[3] = f2bf(v0[3]);
    h[4] = f2bf(v1[0]); h[5] = f2bf(v1[1]); h[6] = f2bf(v1[2]); h[7] = f2bf(v1[3]);
    *reinterpret_cast<bf16x8*>(reinterpret_cast<short*>(abf) + c * 8) = h;
  }
}

// ---------------------------------------------------------------------------
// Main GEMM (m97 structure): 128x128 tile, BK=64, 4 waves (2x2), 4x4 frags.
// Both operands: global_load_lds w=16, linear LDS dest, source pre-swizzled
// with the T2 XOR (byte ^= ((row&7)<<4)); reads apply the same XOR.
// ---------------------------------------------------------------------------
__global__ __launch_bounds__(256, 2)
void cgemm(const __hip_bfloat16* __restrict__ abf,
           const __hip_bfloat16* __restrict__ bt, float* __restrict__ out) {
  __shared__ short Alds[128 * 64];  // [row][k] bf16, swizzled
  __shared__ short Blds[128 * 64];

  const int tid = threadIdx.x;
  const int lane = tid & 63;
  const int wid = tid >> 6;
  const int wr = wid >> 1, wc = wid & 1;
  const int fr_ = lane & 15;
  const int fq = lane >> 4;

  // XCD-aware swizzle (nwg = 4096, %8==0), n-tile fastest.
  const int nwg = gridDim.x;
  const int bid = blockIdx.x;
  const int swz = (bid & 7) * (nwg >> 3) + (bid >> 3);
  const int mt = swz >> 4;   // 0..255
  const int nt = swz & 15;   // 0..15
  const size_t mbase = (size_t)mt * 128;
  const int nbase = nt * 128;

  f32x4 acc[4][4];
  const f32x4 zero = {0.f, 0.f, 0.f, 0.f};
#pragma unroll
  for (int i = 0; i < 4; ++i)
#pragma unroll
    for (int j = 0; j < 4; ++j) acc[i][j] = zero;

  const char* arow0 = (const char*)abf + mbase * 4096;        // row stride 4096 B
  const char* brow0 = (const char*)bt + (size_t)nbase * 4096;

  for (int kt = 0; kt < 32; ++kt) {
    const int k0b = kt * 128;  // byte offset of this K-tile within a row

    __syncthreads();  // previous tile's LDS reads complete

#pragma unroll
    for (int i = 0; i < 4; ++i) {
      int chunk = i * 256 + tid;          // 16-B chunk id (1024 per operand)
      int row = chunk >> 3;               // 0..127
      int kb = (chunk & 7) * 16;          // byte within 128-B row slice
      int off = row * 4096 + k0b + (kb ^ ((row & 7) << 4));
      __builtin_amdgcn_global_load_lds((gas_ptr)(arow0 + off),
                                       (las_ptr)((char*)Alds + chunk * 16),
                                       16, 0, 0);
      __builtin_amdgcn_global_load_lds((gas_ptr)(brow0 + off),
                                       (las_ptr)((char*)Blds + chunk * 16),
                                       16, 0, 0);
    }

    __syncthreads();  // drains vmcnt: staged tile visible

#pragma unroll
    for (int ks = 0; ks < 2; ++ks) {
      bf16x8 af[4], bfr[4];
      const int koff = ks * 64 + fq * 16;
#pragma unroll
      for (int mi = 0; mi < 4; ++mi) {
        int row = wr * 64 + mi * 16 + fr_;
        int byte = (row * 128 + koff) ^ ((row & 7) << 4);
        af[mi] = *reinterpret_cast<const bf16x8*>(
            reinterpret_cast<const char*>(Alds) + byte);
      }
#pragma unroll
      for (int ni = 0; ni < 4; ++ni) {
        int row = wc * 64 + ni * 16 + fr_;
        int byte = (row * 128 + koff) ^ ((row & 7) << 4);
        bfr[ni] = *reinterpret_cast<const bf16x8*>(
            reinterpret_cast<const char*>(Blds) + byte);
      }
#pragma unroll
      for (int mi = 0; mi < 4; ++mi)
#pragma unroll
        for (int ni = 0; ni < 4; ++ni)
          acc[mi][ni] = __builtin_amdgcn_mfma_f32_16x16x32_bf16(
              af[mi], bfr[ni], acc[mi][ni], 0, 0, 0);
    }
  }

  // Epilogue: C/D layout col=lane&15, row=(lane>>4)*4+reg (m89-verified)
  const size_t half = (size_t)32768 * 1024;
  float* ob = out + ((nbase >= 1024) ? half : 0);
  const int ncol0 = nbase & 1023;
#pragma unroll
  for (int mi = 0; mi < 4; ++mi) {
#pragma unroll
    for (int ni = 0; ni < 4; ++ni) {
      int colg = ncol0 + wc * 64 + ni * 16 + fr_;
      size_t rbase = mbase + wr * 64 + mi * 16 + fq * 4;
#pragma unroll
      for (int j = 0; j < 4; ++j)
        ob[(rbase + j) * 1024 + colg] = acc[mi][ni][j];
    }
  }
}

// ---------------------------------------------------------------------------
// Fallback GEMM (round-1 path): A fp32 reg-staged in-loop. Used only if
// ws_size can't hold the bf16 copy of A.
// ---------------------------------------------------------------------------
__global__ __launch_bounds__(256, 2)
void cgemm_f32a(const float* __restrict__ re, const float* __restrict__ im,
                const __hip_bfloat16* __restrict__ bt, float* __restrict__ out) {
  __shared__ short Alds[128 * 64];
  __shared__ short Blds[128 * 64];

  const int tid = threadIdx.x;
  const int lane = tid & 63;
  const int wid = tid >> 6;
  const int wr = wid >> 1, wc = wid & 1;
  const int fr_ = lane & 15;
  const int fq = lane >> 4;

  const int nwg = gridDim.x;
  const int bid = blockIdx.x;
  const int swz = (bid & 7) * (nwg >> 3) + (bid >> 3);
  const int mt = swz >> 4;
  const int nt = swz & 15;
  const size_t mbase = (size_t)mt * 128;
  const int nbase = nt * 128;

  f32x4 acc[4][4];
  const f32x4 zero = {0.f, 0.f, 0.f, 0.f};
#pragma unroll
  for (int i = 0; i < 4; ++i)
#pragma unroll
    for (int j = 0; j < 4; ++j) acc[i][j] = zero;

  const int arow_l = tid >> 3;
  const int akc = (tid & 7) * 8;
  const size_t aoff = (mbase + arow_l) * 1024 + akc;
  const char* btbase = (const char*)bt + (size_t)nbase * 4096;

  for (int kt = 0; kt < 32; ++kt) {
    const int k0 = kt * 64;
    const float* asrc = (k0 < 1024) ? re : im;
    const int kk = k0 & 1023;

    __syncthreads();

    const char* bsrc = btbase + (size_t)k0 * 2;
#pragma unroll
    for (int i = 0; i < 4; ++i) {
      int chunk = i * 256 + tid;
      int n = chunk >> 3;
      int kb = (chunk & 7) * 16;
      int srcoff = n * 4096 + (kb ^ ((n & 7) << 4));
      __builtin_amdgcn_global_load_lds((gas_ptr)(bsrc + srcoff),
                                       (las_ptr)((char*)Blds + chunk * 16),
                                       16, 0, 0);
    }

#pragma unroll
    for (int i = 0; i < 4; ++i) {
      int row = i * 32 + arow_l;
      const float* p = asrc + aoff + (size_t)i * 32 * 1024 + kk;
      f32x4 v0 = *(const f32x4*)p;
      f32x4 v1 = *(const f32x4*)(p + 4);
      bf16x8 h;
      h[0] = f2bf(v0[0]); h[1] = f2bf(v0[1]); h[2] = f2bf(v0[2]); h[3] = f2bf(v0[3]);
      h[4] = f2bf(v1[0]); h[5] = f2bf(v1[1]); h[6] = f2bf(v1[2]); h[7] = f2bf(v1[3]);
      int byte = (row * 128 + akc * 2) ^ ((row & 7) << 4);
      *reinterpret_cast<bf16x8*>(reinterpret_cast<char*>(Alds) + byte) = h;
    }

    __syncthreads();

#pragma unroll
    for (int ks = 0; ks < 2; ++ks) {
      bf16x8 af[4], bfr[4];
      const int koff = ks * 64 + fq * 16;
#pragma unroll
      for (int mi = 0; mi < 4; ++mi) {
        int row = wr * 64 + mi * 16 + fr_;
        int byte = (row * 128 + koff) ^ ((row & 7) << 4);
        af[mi] = *reinterpret_cast<const bf16x8*>(
            reinterpret_cast<const char*>(Alds) + byte);
      }
#pragma unroll
      for (int ni = 0; ni < 4; ++ni) {
        int row = wc * 64 + ni * 16 + fr_;
        int byte = (row * 128 + koff) ^ ((row & 7) << 4);
        bfr[ni] = *reinterpret_cast<const bf16x8*>(
            reinterpret_cast<const char*>(Blds) + byte);
      }
#pragma unroll
      for (int mi = 0; mi < 4; ++mi)
#pragma unroll
        for (int ni = 0; ni < 4; ++ni)
          acc[mi][ni] = __builtin_amdgcn_mfma_f32_16x16x32_bf16(
              af[mi], bfr[ni], acc[mi][ni], 0, 0, 0);
    }
  }

  const size_t half = (size_t)32768 * 1024;
  float* ob = out + ((nbase >= 1024) ? half : 0);
  const int ncol0 = nbase & 1023;
#pragma unroll
  for (int mi = 0; mi < 4; ++mi) {
#pragma unroll
    for (int ni = 0; ni < 4; ++ni) {
      int colg = ncol0 + wc * 64 + ni * 16 + fr_;
      size_t rbase = mbase + wr * 64 + mi * 16 + fq * 4;
#pragma unroll
      for (int j = 0; j < 4; ++j)
        ob[(rbase + j) * 1024 + colg] = acc[mi][ni][j];
    }
  }
}

extern "C" void kernel_launch(void* const* d_in, const int* in_sizes, int n_in,
                              void* d_out, int out_size, void* d_ws, size_t ws_size,
                              hipStream_t stream) {
  const float* re = (const float*)d_in[0];
  const float* im = (const float*)d_in[1];
  const float* fr = (const float*)d_in[2];
  const float* fi = (const float*)d_in[3];
  float* out = (float*)d_out;

  const size_t BT_BYTES = (size_t)2048 * 2048 * 2;           // 8 MB
  const size_t A_BYTES = (size_t)32768 * 2048 * 2;           // 134 MB
  __hip_bfloat16* bt = (__hip_bfloat16*)d_ws;

  build_bt<<<1024, 256, 0, stream>>>(fr, fi, bt);

  if (ws_size >= BT_BYTES + A_BYTES) {
    __hip_bfloat16* abf = (__hip_bfloat16*)((char*)d_ws + BT_BYTES);
    convert_a<<<2048, 256, 0, stream>>>(re, im, abf);
    cgemm<<<4096, 256, 0, stream>>>(abf, bt, out);
  } else {
    cgemm_f32a<<<4096, 256, 0, stream>>>(re, im, bt, out);
  }
}